// Round 1
// baseline (646.685 us; speedup 1.0000x reference)
//
#include <hip/hip_runtime.h>
#include <math.h>

#define B_   16
#define S_   4096
#define D_   768
#define H_   384
#define NTOK (B_ * S_)
#define KTOP 40
#define NTILES 24          // 384/16 n-tiles
#define KCH    24          // 768/32 k-chunks

typedef __attribute__((ext_vector_type(8))) short bf16x8;
typedef __attribute__((ext_vector_type(4))) float f32x4;

static __device__ __forceinline__ unsigned short f2bf(float x) {
    union { float f; unsigned u; } v; v.f = x;
    unsigned r = v.u + 0x7FFF + ((v.u >> 16) & 1);   // RNE
    return (unsigned short)(r >> 16);
}
static __device__ __forceinline__ float bf2f(unsigned short h) {
    union { unsigned u; float f; } v; v.u = ((unsigned)h) << 16; return v.f;
}

// ---------------------------------------------------------------------------
// Kernel 0: pack W1 (fp32 [768][384]) into MFMA B-fragment layout, bf16 hi/lo.
// Fragment element j of lane: B[k = chunk*32 + (lane>>4)*8 + j][n = ntile*16 + (lane&15)]
// packed[( (ntile*KCH + chunk)*64 + lane )*8 + j]
// ---------------------------------------------------------------------------
__global__ __launch_bounds__(64) void pack_w1(const float* __restrict__ W1,
                                              unsigned short* __restrict__ bh,
                                              unsigned short* __restrict__ bl)
{
    const int nt   = blockIdx.x;        // 0..23
    const int ch   = blockIdx.y;        // 0..23
    const int lane = threadIdx.x;
    const int n    = nt * 16 + (lane & 15);
    const int k0   = ch * 32 + (lane >> 4) * 8;

    unsigned short h8[8], l8[8];
#pragma unroll
    for (int j = 0; j < 8; ++j) {
        const float v = W1[(size_t)(k0 + j) * H_ + n];
        const unsigned short h = f2bf(v);
        h8[j] = h;
        l8[j] = f2bf(v - bf2f(h));
    }
    const size_t base = ((size_t)(nt * KCH + ch) * 64 + lane) * 8;
#pragma unroll
    for (int j = 0; j < 8; ++j) { bh[base + j] = h8[j]; bl[base + j] = l8[j]; }
}

// ---------------------------------------------------------------------------
// Kernel 1: fused scores. Block = 64 tokens x 384 cols. 4 waves; wave w owns
// n-tiles w*6..w*6+5 and all 64 rows (4 m-subtiles of 16).
// v2: NO LDS staging / NO k-loop barriers. Each lane loads its A fragment
// (8 consecutive fp32 of one row) directly from global and splits to bf16
// hi/lo in registers. The 4 waves redundantly convert the same 64 rows, but
// the per-chunk block working set (8 KB) is L1-resident and the VALU convert
// runs on a different pipe than MFMA. Waves free-run -> latency self-hiding.
// 3-term bf16-split MFMA GEMM, fp32-accurate (numerics identical to v1).
// Epilogue: LN + GELU + W2 + sigmoid (unchanged).
// ---------------------------------------------------------------------------
__global__ __launch_bounds__(256) void score_kernel(
    const float* __restrict__ features,
    const unsigned short* __restrict__ bh_g,
    const unsigned short* __restrict__ bl_g,
    const float* __restrict__ b1,
    const float* __restrict__ gamma,
    const float* __restrict__ beta,
    const float* __restrict__ W2,
    const float* __restrict__ b2,
    float* __restrict__ scores)
{
    __shared__ float red[4][64];
    __shared__ float mu_s[64];
    __shared__ float rs_s[64];

    const int tid  = threadIdx.x;
    const int lane = tid & 63;
    const int w    = tid >> 6;
    const int base = blockIdx.x * 64;
    const int cl   = lane & 15;
    const int p    = lane >> 4;

    f32x4 acc[4][6];
#pragma unroll
    for (int m = 0; m < 4; ++m)
#pragma unroll
        for (int t = 0; t < 6; ++t) acc[m][t] = (f32x4){0.f, 0.f, 0.f, 0.f};

    // per-lane A row bases (row = base + m*16 + cl), k offset = c*32 + p*8
    const float* arow[4];
#pragma unroll
    for (int m = 0; m < 4; ++m)
        arow[m] = features + (size_t)(base + m * 16 + cl) * D_ + p * 8;

#pragma unroll 2
    for (int c = 0; c < KCH; ++c) {
        // --- A loads first (convert below waits only on these) ---
        float4 araw0[4], araw1[4];
#pragma unroll
        for (int m = 0; m < 4; ++m) {
            const float* src = arow[m] + c * 32;
            araw0[m] = *(const float4*)(src);
            araw1[m] = *(const float4*)(src + 4);
        }
        // --- B fragment loads (L2-resident packed W1) ---
        bf16x8 bhf[6], blf[6];
#pragma unroll
        for (int t = 0; t < 6; ++t) {
            const size_t bb = ((size_t)((w * 6 + t) * KCH + c) * 64 + lane) * 8;
            bhf[t] = *(const bf16x8*)(bh_g + bb);
            blf[t] = *(const bf16x8*)(bl_g + bb);
        }
        // --- split A to bf16 hi/lo in registers (overlaps B latency) ---
        bf16x8 ahf[4], alf[4];
#pragma unroll
        for (int m = 0; m < 4; ++m) {
            float f[8] = {araw0[m].x, araw0[m].y, araw0[m].z, araw0[m].w,
                          araw1[m].x, araw1[m].y, araw1[m].z, araw1[m].w};
            bf16x8 hv, lv;
#pragma unroll
            for (int j = 0; j < 8; ++j) {
                const unsigned short hh = f2bf(f[j]);
                hv[j] = (short)hh;
                lv[j] = (short)f2bf(f[j] - bf2f(hh));
            }
            ahf[m] = hv; alf[m] = lv;
        }
        // --- MFMA: 4 m-subtiles x 6 n-tiles x 3 split terms ---
#pragma unroll
        for (int m = 0; m < 4; ++m)
#pragma unroll
            for (int t = 0; t < 6; ++t) {
                acc[m][t] = __builtin_amdgcn_mfma_f32_16x16x32_bf16(ahf[m], bhf[t], acc[m][t], 0, 0, 0);
                acc[m][t] = __builtin_amdgcn_mfma_f32_16x16x32_bf16(ahf[m], blf[t], acc[m][t], 0, 0, 0);
                acc[m][t] = __builtin_amdgcn_mfma_f32_16x16x32_bf16(alf[m], bhf[t], acc[m][t], 0, 0, 0);
            }
    }

    // ---- epilogue: per-column constants ----
    float b1v[6], gv[6], bev[6], w2v[6];
#pragma unroll
    for (int t = 0; t < 6; ++t) {
        const int n = (w * 6 + t) * 16 + cl;
        b1v[t] = b1[n]; gv[t] = gamma[n]; bev[t] = beta[n]; w2v[t] = W2[n];
    }
    // h = acc + b1
#pragma unroll
    for (int m = 0; m < 4; ++m)
#pragma unroll
        for (int t = 0; t < 6; ++t)
#pragma unroll
            for (int r = 0; r < 4; ++r) acc[m][t][r] += b1v[t];

    // pass 1: row sums -> mean
#pragma unroll
    for (int m = 0; m < 4; ++m) {
        float sm[4] = {0.f, 0.f, 0.f, 0.f};
#pragma unroll
        for (int t = 0; t < 6; ++t)
#pragma unroll
            for (int r = 0; r < 4; ++r) sm[r] += acc[m][t][r];
#pragma unroll
        for (int r = 0; r < 4; ++r) {
#pragma unroll
            for (int off = 1; off <= 8; off <<= 1) sm[r] += __shfl_xor(sm[r], off, 64);
        }
        if (cl == 0) {
#pragma unroll
            for (int r = 0; r < 4; ++r) red[w][m * 16 + p * 4 + r] = sm[r];
        }
    }
    __syncthreads();
    if (tid < 64) mu_s[tid] = (red[0][tid] + red[1][tid] + red[2][tid] + red[3][tid]) * (1.0f / H_);
    __syncthreads();

    // pass 2: variance (two-pass, matches reference)
#pragma unroll
    for (int m = 0; m < 4; ++m) {
        float mur[4];
#pragma unroll
        for (int r = 0; r < 4; ++r) mur[r] = mu_s[m * 16 + p * 4 + r];
        float sm[4] = {0.f, 0.f, 0.f, 0.f};
#pragma unroll
        for (int t = 0; t < 6; ++t)
#pragma unroll
            for (int r = 0; r < 4; ++r) { const float d = acc[m][t][r] - mur[r]; sm[r] += d * d; }
#pragma unroll
        for (int r = 0; r < 4; ++r) {
#pragma unroll
            for (int off = 1; off <= 8; off <<= 1) sm[r] += __shfl_xor(sm[r], off, 64);
        }
        if (cl == 0) {
#pragma unroll
            for (int r = 0; r < 4; ++r) red[w][m * 16 + p * 4 + r] = sm[r];
        }
    }
    __syncthreads();
    if (tid < 64) rs_s[tid] = rsqrtf((red[0][tid] + red[1][tid] + red[2][tid] + red[3][tid]) * (1.0f / H_) + 1e-5f);
    __syncthreads();

    // pass 3: y = LN*gamma+beta, gelu, dot with W2
#pragma unroll
    for (int m = 0; m < 4; ++m) {
        float mur[4], rsr[4];
#pragma unroll
        for (int r = 0; r < 4; ++r) { mur[r] = mu_s[m * 16 + p * 4 + r]; rsr[r] = rs_s[m * 16 + p * 4 + r]; }
        float sm[4] = {0.f, 0.f, 0.f, 0.f};
#pragma unroll
        for (int t = 0; t < 6; ++t)
#pragma unroll
            for (int r = 0; r < 4; ++r) {
                const float y  = (acc[m][t][r] - mur[r]) * rsr[r] * gv[t] + bev[t];
                const float ge = 0.5f * y * (1.0f + erff(y * 0.70710678118654752f));
                sm[r] = fmaf(ge, w2v[t], sm[r]);
            }
#pragma unroll
        for (int r = 0; r < 4; ++r) {
#pragma unroll
            for (int off = 1; off <= 8; off <<= 1) sm[r] += __shfl_xor(sm[r], off, 64);
        }
        if (cl == 0) {
#pragma unroll
            for (int r = 0; r < 4; ++r) red[w][m * 16 + p * 4 + r] = sm[r];
        }
    }
    __syncthreads();
    if (tid < 64) {
        const float s = red[0][tid] + red[1][tid] + red[2][tid] + red[3][tid] + b2[0];
        scores[base + tid] = 1.0f / (1.0f + expf(-s));
    }
}

// ---------------------------------------------------------------------------
// Kernel 2: per-batch exact top-40 via byte-wise radix select on float bits
// (scores > 0 so uint order == float order). Ties -> lower index.
// ---------------------------------------------------------------------------
__global__ __launch_bounds__(256) void select_kernel(const float* __restrict__ scores,
                                                     int* __restrict__ sel)
{
    __shared__ unsigned int bits_s[S_];     // 16 KB
    __shared__ unsigned int hist[256];
    __shared__ int s_byte, s_above, s_rem;
    __shared__ unsigned int s_ngt, s_neq;
    __shared__ unsigned int candV[64];
    __shared__ int candI[64];
    __shared__ int eqI[256];

    const int b   = blockIdx.x;
    const int tid = threadIdx.x;

    for (int i = tid; i < S_; i += 256)
        bits_s[i] = __float_as_uint(scores[b * S_ + i]);
    if (tid == 0) { s_rem = KTOP; s_ngt = 0u; s_neq = 0u; }

    unsigned int prefix = 0u, mask = 0u;
    for (int pb = 3; pb >= 0; --pb) {
        hist[tid] = 0u;
        __syncthreads();
        for (int i = tid; i < S_; i += 256) {
            const unsigned int u = bits_s[i];
            if ((u & mask) == prefix) atomicAdd(&hist[(u >> (8 * pb)) & 255u], 1u);
        }
        __syncthreads();
        if (tid == 0) {
            int c = 0, v = 255;
            for (; v >= 0; --v) { c += (int)hist[v]; if (c >= s_rem) break; }
            s_byte  = v;
            s_above = c - (int)hist[v];
            s_rem   = s_rem - s_above;
        }
        __syncthreads();
        prefix |= ((unsigned int)s_byte) << (8 * pb);
        mask   |= 0xFFu << (8 * pb);
        __syncthreads();
    }
    const unsigned int T = prefix;
    const int need = s_rem;                 // 1..: #ties at T to keep

    for (int i = tid; i < S_; i += 256) {
        const unsigned int u = bits_s[i];
        if (u > T) {
            const unsigned int pos = atomicAdd(&s_ngt, 1u);
            candV[pos] = u; candI[pos] = i;          // n_gt <= 39 guaranteed
        } else if (u == T) {
            const unsigned int pos = atomicAdd(&s_neq, 1u);
            if (pos < 256u) eqI[pos] = i;
        }
    }
    __syncthreads();
    const int ngt = (int)s_ngt;
    const int neq = (int)(s_neq < 256u ? s_neq : 256u);
    // keep the `need` smallest indices among ties
    for (int j = tid; j < neq; j += 256) {
        int rank = 0;
        for (int l = 0; l < neq; ++l) rank += (eqI[l] < eqI[j]) ? 1 : 0;
        if (rank < need) { candV[ngt + rank] = T; candI[ngt + rank] = eqI[j]; }
    }
    __syncthreads();
    // final ordering: (score desc, index asc)
    if (tid < KTOP) {
        const unsigned int u = candV[tid];
        const int idx = candI[tid];
        int rank = 0;
        for (int j = 0; j < KTOP; ++j)
            rank += (candV[j] > u || (candV[j] == u && candI[j] < idx)) ? 1 : 0;
        sel[b * KTOP + rank] = idx;
    }
}

// ---------------------------------------------------------------------------
// Kernel 3: gather selected rows + write indices (as float). Grid (40,16).
// ---------------------------------------------------------------------------
__global__ __launch_bounds__(192) void gather_kernel(const float* __restrict__ features,
                                                     const int* __restrict__ sel,
                                                     float* __restrict__ out_tok,
                                                     float* __restrict__ out_idx)
{
    const int i = blockIdx.x;   // 0..39
    const int b = blockIdx.y;   // 0..15
    const int idx = sel[b * KTOP + i];
    const float4* src = (const float4*)(features + ((size_t)b * S_ + idx) * D_);
    float4* dst = (float4*)(out_tok + ((size_t)b * KTOP + i) * D_);
    dst[threadIdx.x] = src[threadIdx.x];
    if (threadIdx.x == 0) out_idx[b * KTOP + i] = (float)idx;
}

// ---------------------------------------------------------------------------
extern "C" void kernel_launch(void* const* d_in, const int* in_sizes, int n_in,
                              void* d_out, int out_size, void* d_ws, size_t ws_size,
                              hipStream_t stream)
{
    const float* features = (const float*)d_in[0];
    const float* W1       = (const float*)d_in[1];
    const float* b1       = (const float*)d_in[2];
    const float* gamma    = (const float*)d_in[3];
    const float* beta     = (const float*)d_in[4];
    const float* W2       = (const float*)d_in[5];
    const float* b2       = (const float*)d_in[6];

    // ws layout
    unsigned short* bh = (unsigned short*)d_ws;            // 294912 elems (576 KB)
    unsigned short* bl = bh + (size_t)D_ * H_;             // 576 KB
    float* scores      = (float*)(bl + (size_t)D_ * H_);   // 256 KB
    int*   sel         = (int*)(scores + NTOK);            // 2.5 KB

    float* out        = (float*)d_out;
    float* out_tokens = out;                               // [16,40,768]
    float* out_idx    = out + (size_t)B_ * KTOP * D_;      // [16,40]

    pack_w1<<<dim3(NTILES, KCH), 64, 0, stream>>>(W1, bh, bl);
    score_kernel<<<NTOK / 64, 256, 0, stream>>>(features, bh, bl, b1, gamma, beta, W2, b2, scores);
    select_kernel<<<B_, 256, 0, stream>>>(scores, sel);
    gather_kernel<<<dim3(KTOP, B_), 192, 0, stream>>>(features, sel, out_tokens, out_idx);
}

// Round 2
// 457.037 us; speedup vs baseline: 1.4150x; 1.4150x over previous
//
#include <hip/hip_runtime.h>
#include <math.h>

#define B_   16
#define S_   4096
#define D_   768
#define H_   384
#define NTOK (B_ * S_)
#define KTOP 40
#define NTILES 24          // 384/16 n-tiles
#define KCH    24          // 768/32 k-chunks

typedef __attribute__((ext_vector_type(8))) short bf16x8;
typedef __attribute__((ext_vector_type(4))) float f32x4;

static __device__ __forceinline__ unsigned short f2bf(float x) {
    union { float f; unsigned u; } v; v.f = x;
    unsigned r = v.u + 0x7FFF + ((v.u >> 16) & 1);   // RNE
    return (unsigned short)(r >> 16);
}
static __device__ __forceinline__ float bf2f(unsigned short h) {
    union { unsigned u; float f; } v; v.u = ((unsigned)h) << 16; return v.f;
}

// ---------------------------------------------------------------------------
// Kernel 0: pack W1 (fp32 [768][384]) into MFMA B-fragment layout, bf16 hi/lo.
// Fragment element j of lane: B[k = chunk*32 + (lane>>4)*8 + j][n = ntile*16 + (lane&15)]
// packed[( (ntile*KCH + chunk)*64 + lane )*8 + j]
// ---------------------------------------------------------------------------
__global__ __launch_bounds__(64) void pack_w1(const float* __restrict__ W1,
                                              unsigned short* __restrict__ bh,
                                              unsigned short* __restrict__ bl)
{
    const int nt   = blockIdx.x;        // 0..23
    const int ch   = blockIdx.y;        // 0..23
    const int lane = threadIdx.x;
    const int n    = nt * 16 + (lane & 15);
    const int k0   = ch * 32 + (lane >> 4) * 8;

    unsigned short h8[8], l8[8];
#pragma unroll
    for (int j = 0; j < 8; ++j) {
        const float v = W1[(size_t)(k0 + j) * H_ + n];
        const unsigned short h = f2bf(v);
        h8[j] = h;
        l8[j] = f2bf(v - bf2f(h));
    }
    const size_t base = ((size_t)(nt * KCH + ch) * 64 + lane) * 8;
#pragma unroll
    for (int j = 0; j < 8; ++j) { bh[base + j] = h8[j]; bl[base + j] = l8[j]; }
}

// ---------------------------------------------------------------------------
// Kernel 1: fused scores. v3: block = 32 tokens x 384 cols (grid 2048).
// 4 waves; wave w owns n-tiles w*6..w*6+5 and 2 m-subtiles of 16 rows.
// acc = 48 VGPR (was 96) and __launch_bounds__(256,3) forces <=170 regs so
// 3 blocks/CU co-reside (v1/v2 had 1 -> zero TLP, both pipes <20%).
// LDS-staged shared fp32->bf16-split convert (v1 style, cheap VALU).
// 3-term bf16-split MFMA, identical accumulation order -> scores bitwise
// identical to v1/v2 (absmax 0 preserved).
// ---------------------------------------------------------------------------
__global__ __launch_bounds__(256, 3) void score_kernel(
    const float* __restrict__ features,
    const unsigned short* __restrict__ bh_g,
    const unsigned short* __restrict__ bl_g,
    const float* __restrict__ b1,
    const float* __restrict__ gamma,
    const float* __restrict__ beta,
    const float* __restrict__ W2,
    const float* __restrict__ b2,
    float* __restrict__ scores)
{
    __shared__ unsigned short Ah[32][40];   // pad 32->40: 2-way bank alias only
    __shared__ unsigned short Al[32][40];
    __shared__ float red[4][32];
    __shared__ float mu_s[32];
    __shared__ float rs_s[32];

    const int tid  = threadIdx.x;
    const int lane = tid & 63;
    const int w    = tid >> 6;
    const int base = blockIdx.x * 32;
    const int cl   = lane & 15;
    const int p    = lane >> 4;

    f32x4 acc[2][6];
#pragma unroll
    for (int m = 0; m < 2; ++m)
#pragma unroll
        for (int t = 0; t < 6; ++t) acc[m][t] = (f32x4){0.f, 0.f, 0.f, 0.f};

    // staging map: thread covers one float4: row = tid>>3 (0..31), col4 = (tid&7)*4
    const int r0 = tid >> 3, c0 = (tid & 7) * 4;

    float4 p0 = *(const float4*)(features + (size_t)(base + r0) * D_ + c0);

    for (int c = 0; c < KCH; ++c) {
        if (c) __syncthreads();
        // convert + write staged chunk
        {
            unsigned short h0 = f2bf(p0.x), h1 = f2bf(p0.y), h2 = f2bf(p0.z), h3 = f2bf(p0.w);
            Ah[r0][c0] = h0; Ah[r0][c0+1] = h1; Ah[r0][c0+2] = h2; Ah[r0][c0+3] = h3;
            Al[r0][c0]   = f2bf(p0.x - bf2f(h0));
            Al[r0][c0+1] = f2bf(p0.y - bf2f(h1));
            Al[r0][c0+2] = f2bf(p0.z - bf2f(h2));
            Al[r0][c0+3] = f2bf(p0.w - bf2f(h3));
        }
        // prefetch next chunk (overlaps barrier + MFMA below)
        if (c + 1 < KCH) {
            const int d0 = (c + 1) * 32;
            p0 = *(const float4*)(features + (size_t)(base + r0) * D_ + d0 + c0);
        }
        __syncthreads();

        // A fragments for the 2 m-subtiles
        bf16x8 ahf[2], alf[2];
#pragma unroll
        for (int m = 0; m < 2; ++m) {
            const int row = m * 16 + cl;
            const int k0  = p * 8;
            ahf[m] = *(const bf16x8*)&Ah[row][k0];
            alf[m] = *(const bf16x8*)&Al[row][k0];
        }
        // B fragments per n-tile, MFMA immediately (limits B liveness)
#pragma unroll
        for (int t = 0; t < 6; ++t) {
            const size_t bb = ((size_t)((w * 6 + t) * KCH + c) * 64 + lane) * 8;
            const bf16x8 bhf = *(const bf16x8*)(bh_g + bb);
            const bf16x8 blf = *(const bf16x8*)(bl_g + bb);
#pragma unroll
            for (int m = 0; m < 2; ++m) {
                acc[m][t] = __builtin_amdgcn_mfma_f32_16x16x32_bf16(ahf[m], bhf, acc[m][t], 0, 0, 0);
                acc[m][t] = __builtin_amdgcn_mfma_f32_16x16x32_bf16(ahf[m], blf, acc[m][t], 0, 0, 0);
                acc[m][t] = __builtin_amdgcn_mfma_f32_16x16x32_bf16(alf[m], bhf, acc[m][t], 0, 0, 0);
            }
        }
    }

    // ---- epilogue: per-column constants ----
    float b1v[6], gv[6], bev[6], w2v[6];
#pragma unroll
    for (int t = 0; t < 6; ++t) {
        const int n = (w * 6 + t) * 16 + cl;
        b1v[t] = b1[n]; gv[t] = gamma[n]; bev[t] = beta[n]; w2v[t] = W2[n];
    }
    // h = acc + b1
#pragma unroll
    for (int m = 0; m < 2; ++m)
#pragma unroll
        for (int t = 0; t < 6; ++t)
#pragma unroll
            for (int r = 0; r < 4; ++r) acc[m][t][r] += b1v[t];

    // pass 1: row sums -> mean
#pragma unroll
    for (int m = 0; m < 2; ++m) {
        float sm[4] = {0.f, 0.f, 0.f, 0.f};
#pragma unroll
        for (int t = 0; t < 6; ++t)
#pragma unroll
            for (int r = 0; r < 4; ++r) sm[r] += acc[m][t][r];
#pragma unroll
        for (int r = 0; r < 4; ++r) {
#pragma unroll
            for (int off = 1; off <= 8; off <<= 1) sm[r] += __shfl_xor(sm[r], off, 64);
        }
        if (cl == 0) {
#pragma unroll
            for (int r = 0; r < 4; ++r) red[w][m * 16 + p * 4 + r] = sm[r];
        }
    }
    __syncthreads();
    if (tid < 32) mu_s[tid] = (red[0][tid] + red[1][tid] + red[2][tid] + red[3][tid]) * (1.0f / H_);
    __syncthreads();

    // pass 2: variance (two-pass, matches reference)
#pragma unroll
    for (int m = 0; m < 2; ++m) {
        float mur[4];
#pragma unroll
        for (int r = 0; r < 4; ++r) mur[r] = mu_s[m * 16 + p * 4 + r];
        float sm[4] = {0.f, 0.f, 0.f, 0.f};
#pragma unroll
        for (int t = 0; t < 6; ++t)
#pragma unroll
            for (int r = 0; r < 4; ++r) { const float d = acc[m][t][r] - mur[r]; sm[r] += d * d; }
#pragma unroll
        for (int r = 0; r < 4; ++r) {
#pragma unroll
            for (int off = 1; off <= 8; off <<= 1) sm[r] += __shfl_xor(sm[r], off, 64);
        }
        if (cl == 0) {
#pragma unroll
            for (int r = 0; r < 4; ++r) red[w][m * 16 + p * 4 + r] = sm[r];
        }
    }
    __syncthreads();
    if (tid < 32) rs_s[tid] = rsqrtf((red[0][tid] + red[1][tid] + red[2][tid] + red[3][tid]) * (1.0f / H_) + 1e-5f);
    __syncthreads();

    // pass 3: y = LN*gamma+beta, gelu, dot with W2
#pragma unroll
    for (int m = 0; m < 2; ++m) {
        float mur[4], rsr[4];
#pragma unroll
        for (int r = 0; r < 4; ++r) { mur[r] = mu_s[m * 16 + p * 4 + r]; rsr[r] = rs_s[m * 16 + p * 4 + r]; }
        float sm[4] = {0.f, 0.f, 0.f, 0.f};
#pragma unroll
        for (int t = 0; t < 6; ++t)
#pragma unroll
            for (int r = 0; r < 4; ++r) {
                const float y  = (acc[m][t][r] - mur[r]) * rsr[r] * gv[t] + bev[t];
                const float ge = 0.5f * y * (1.0f + erff(y * 0.70710678118654752f));
                sm[r] = fmaf(ge, w2v[t], sm[r]);
            }
#pragma unroll
        for (int r = 0; r < 4; ++r) {
#pragma unroll
            for (int off = 1; off <= 8; off <<= 1) sm[r] += __shfl_xor(sm[r], off, 64);
        }
        if (cl == 0) {
#pragma unroll
            for (int r = 0; r < 4; ++r) red[w][m * 16 + p * 4 + r] = sm[r];
        }
    }
    __syncthreads();
    if (tid < 32) {
        const float s = red[0][tid] + red[1][tid] + red[2][tid] + red[3][tid] + b2[0];
        scores[base + tid] = 1.0f / (1.0f + expf(-s));
    }
}

// ---------------------------------------------------------------------------
// Kernel 2: per-batch exact top-40 via byte-wise radix select on float bits
// (scores > 0 so uint order == float order). Ties -> lower index.
// ---------------------------------------------------------------------------
__global__ __launch_bounds__(256) void select_kernel(const float* __restrict__ scores,
                                                     int* __restrict__ sel)
{
    __shared__ unsigned int bits_s[S_];     // 16 KB
    __shared__ unsigned int hist[256];
    __shared__ int s_byte, s_above, s_rem;
    __shared__ unsigned int s_ngt, s_neq;
    __shared__ unsigned int candV[64];
    __shared__ int candI[64];
    __shared__ int eqI[256];

    const int b   = blockIdx.x;
    const int tid = threadIdx.x;

    for (int i = tid; i < S_; i += 256)
        bits_s[i] = __float_as_uint(scores[b * S_ + i]);
    if (tid == 0) { s_rem = KTOP; s_ngt = 0u; s_neq = 0u; }

    unsigned int prefix = 0u, mask = 0u;
    for (int pb = 3; pb >= 0; --pb) {
        hist[tid] = 0u;
        __syncthreads();
        for (int i = tid; i < S_; i += 256) {
            const unsigned int u = bits_s[i];
            if ((u & mask) == prefix) atomicAdd(&hist[(u >> (8 * pb)) & 255u], 1u);
        }
        __syncthreads();
        if (tid == 0) {
            int c = 0, v = 255;
            for (; v >= 0; --v) { c += (int)hist[v]; if (c >= s_rem) break; }
            s_byte  = v;
            s_above = c - (int)hist[v];
            s_rem   = s_rem - s_above;
        }
        __syncthreads();
        prefix |= ((unsigned int)s_byte) << (8 * pb);
        mask   |= 0xFFu << (8 * pb);
        __syncthreads();
    }
    const unsigned int T = prefix;
    const int need = s_rem;                 // 1..: #ties at T to keep

    for (int i = tid; i < S_; i += 256) {
        const unsigned int u = bits_s[i];
        if (u > T) {
            const unsigned int pos = atomicAdd(&s_ngt, 1u);
            candV[pos] = u; candI[pos] = i;          // n_gt <= 39 guaranteed
        } else if (u == T) {
            const unsigned int pos = atomicAdd(&s_neq, 1u);
            if (pos < 256u) eqI[pos] = i;
        }
    }
    __syncthreads();
    const int ngt = (int)s_ngt;
    const int neq = (int)(s_neq < 256u ? s_neq : 256u);
    // keep the `need` smallest indices among ties
    for (int j = tid; j < neq; j += 256) {
        int rank = 0;
        for (int l = 0; l < neq; ++l) rank += (eqI[l] < eqI[j]) ? 1 : 0;
        if (rank < need) { candV[ngt + rank] = T; candI[ngt + rank] = eqI[j]; }
    }
    __syncthreads();
    // final ordering: (score desc, index asc)
    if (tid < KTOP) {
        const unsigned int u = candV[tid];
        const int idx = candI[tid];
        int rank = 0;
        for (int j = 0; j < KTOP; ++j)
            rank += (candV[j] > u || (candV[j] == u && candI[j] < idx)) ? 1 : 0;
        sel[b * KTOP + rank] = idx;
    }
}

// ---------------------------------------------------------------------------
// Kernel 3: gather selected rows + write indices (as float). Grid (40,16).
// ---------------------------------------------------------------------------
__global__ __launch_bounds__(192) void gather_kernel(const float* __restrict__ features,
                                                     const int* __restrict__ sel,
                                                     float* __restrict__ out_tok,
                                                     float* __restrict__ out_idx)
{
    const int i = blockIdx.x;   // 0..39
    const int b = blockIdx.y;   // 0..15
    const int idx = sel[b * KTOP + i];
    const float4* src = (const float4*)(features + ((size_t)b * S_ + idx) * D_);
    float4* dst = (float4*)(out_tok + ((size_t)b * KTOP + i) * D_);
    dst[threadIdx.x] = src[threadIdx.x];
    if (threadIdx.x == 0) out_idx[b * KTOP + i] = (float)idx;
}

// ---------------------------------------------------------------------------
extern "C" void kernel_launch(void* const* d_in, const int* in_sizes, int n_in,
                              void* d_out, int out_size, void* d_ws, size_t ws_size,
                              hipStream_t stream)
{
    const float* features = (const float*)d_in[0];
    const float* W1       = (const float*)d_in[1];
    const float* b1       = (const float*)d_in[2];
    const float* gamma    = (const float*)d_in[3];
    const float* beta     = (const float*)d_in[4];
    const float* W2       = (const float*)d_in[5];
    const float* b2       = (const float*)d_in[6];

    // ws layout
    unsigned short* bh = (unsigned short*)d_ws;            // 294912 elems (576 KB)
    unsigned short* bl = bh + (size_t)D_ * H_;             // 576 KB
    float* scores      = (float*)(bl + (size_t)D_ * H_);   // 256 KB
    int*   sel         = (int*)(scores + NTOK);            // 2.5 KB

    float* out        = (float*)d_out;
    float* out_tokens = out;                               // [16,40,768]
    float* out_idx    = out + (size_t)B_ * KTOP * D_;      // [16,40]

    pack_w1<<<dim3(NTILES, KCH), 64, 0, stream>>>(W1, bh, bl);
    score_kernel<<<NTOK / 32, 256, 0, stream>>>(features, bh, bl, b1, gamma, beta, W2, b2, scores);
    select_kernel<<<B_, 256, 0, stream>>>(scores, sel);
    gather_kernel<<<dim3(KTOP, B_), 192, 0, stream>>>(features, sel, out_tokens, out_idx);
}

// Round 3
// 429.643 us; speedup vs baseline: 1.5052x; 1.0638x over previous
//
#include <hip/hip_runtime.h>
#include <math.h>

#define B_   16
#define S_   4096
#define D_   768
#define H_   384
#define NTOK (B_ * S_)
#define KTOP 40
#define NTILES 24          // 384/16 n-tiles
#define KCH    24          // 768/32 k-chunks

typedef __attribute__((ext_vector_type(8))) short bf16x8;
typedef __attribute__((ext_vector_type(4))) float f32x4;

static __device__ __forceinline__ unsigned short f2bf(float x) {
    union { float f; unsigned u; } v; v.f = x;
    unsigned r = v.u + 0x7FFF + ((v.u >> 16) & 1);   // RNE
    return (unsigned short)(r >> 16);
}
static __device__ __forceinline__ float bf2f(unsigned short h) {
    union { unsigned u; float f; } v; v.u = ((unsigned)h) << 16; return v.f;
}

// ---------------------------------------------------------------------------
// Kernel 0: pack W1 (fp32 [768][384]) into MFMA B-fragment layout, bf16 hi/lo.
// Fragment element j of lane: B[k = chunk*32 + (lane>>4)*8 + j][n = ntile*16 + (lane&15)]
// packed[( (ntile*KCH + chunk)*64 + lane )*8 + j]
// ---------------------------------------------------------------------------
__global__ __launch_bounds__(64) void pack_w1(const float* __restrict__ W1,
                                              unsigned short* __restrict__ bh,
                                              unsigned short* __restrict__ bl)
{
    const int nt   = blockIdx.x;        // 0..23
    const int ch   = blockIdx.y;        // 0..23
    const int lane = threadIdx.x;
    const int n    = nt * 16 + (lane & 15);
    const int k0   = ch * 32 + (lane >> 4) * 8;

    unsigned short h8[8], l8[8];
#pragma unroll
    for (int j = 0; j < 8; ++j) {
        const float v = W1[(size_t)(k0 + j) * H_ + n];
        const unsigned short h = f2bf(v);
        h8[j] = h;
        l8[j] = f2bf(v - bf2f(h));
    }
    const size_t base = ((size_t)(nt * KCH + ch) * 64 + lane) * 8;
#pragma unroll
    for (int j = 0; j < 8; ++j) { bh[base + j] = h8[j]; bl[base + j] = l8[j]; }
}

// ---------------------------------------------------------------------------
// Kernel 1: fused scores. v4: block = 32 tokens x 384 cols (grid 2048),
// 4 waves, wave w owns n-tiles w*6..w*6+5 and 2 m-subtiles (acc 48).
// NEW: pair staging (2 K-chunks / iteration) into a 4-slot double-buffered
// LDS ring -> ONE barrier per iteration (13 total vs v3's 48). Iteration i
// reads slots {2i,2i+1}&3, writes {2i+2,2i+3}&3 (disjoint); barrier orders
// next iteration's writes against this one's reads. Global prefetch issued
// at iteration start, convert+write at iteration end (~700cy cover).
// Accumulation order identical to v3 -> scores bitwise identical.
// __launch_bounds__(256,4): combined VGPR<=128 pins 4 blocks/CU.
// ---------------------------------------------------------------------------
__global__ __launch_bounds__(256, 4) void score_kernel(
    const float* __restrict__ features,
    const unsigned short* __restrict__ bh_g,
    const unsigned short* __restrict__ bl_g,
    const float* __restrict__ b1,
    const float* __restrict__ gamma,
    const float* __restrict__ beta,
    const float* __restrict__ W2,
    const float* __restrict__ b2,
    float* __restrict__ scores)
{
    __shared__ unsigned short Ah[4][32][40];   // 4-slot ring, pad 32->40
    __shared__ unsigned short Al[4][32][40];
    __shared__ float red[4][32];
    __shared__ float mu_s[32];
    __shared__ float rs_s[32];

    const int tid  = threadIdx.x;
    const int lane = tid & 63;
    const int w    = tid >> 6;
    const int base = blockIdx.x * 32;
    const int cl   = lane & 15;
    const int p    = lane >> 4;

    f32x4 acc[2][6];
#pragma unroll
    for (int m = 0; m < 2; ++m)
#pragma unroll
        for (int t = 0; t < 6; ++t) acc[m][t] = (f32x4){0.f, 0.f, 0.f, 0.f};

    // staging map: thread covers one float4 per chunk of the pair:
    // row = tid>>3 (0..31), col4 = (tid&7)*4
    const int r0 = tid >> 3, c0 = (tid & 7) * 4;
    const float* arow = features + (size_t)(base + r0) * D_ + c0;

#define STAGE(vec, slot)                                                      \
    do {                                                                      \
        const float4 _v = (vec);                                              \
        unsigned short h0 = f2bf(_v.x), h1 = f2bf(_v.y),                      \
                       h2 = f2bf(_v.z), h3 = f2bf(_v.w);                      \
        Ah[slot][r0][c0]   = h0; Ah[slot][r0][c0+1] = h1;                     \
        Ah[slot][r0][c0+2] = h2; Ah[slot][r0][c0+3] = h3;                     \
        Al[slot][r0][c0]   = f2bf(_v.x - bf2f(h0));                           \
        Al[slot][r0][c0+1] = f2bf(_v.y - bf2f(h1));                           \
        Al[slot][r0][c0+2] = f2bf(_v.z - bf2f(h2));                           \
        Al[slot][r0][c0+3] = f2bf(_v.w - bf2f(h3));                           \
    } while (0)

    // prologue: stage chunks 0,1 into slots 0,1
    float4 q0 = *(const float4*)(arow + 0 * 32);
    float4 q1 = *(const float4*)(arow + 1 * 32);
    STAGE(q0, 0);
    STAGE(q1, 1);
    __syncthreads();

    for (int i = 0; i < 12; ++i) {
        // prefetch next pair (lands under this iteration's compute)
        if (i < 11) {
            q0 = *(const float4*)(arow + (2 * i + 2) * 32);
            q1 = *(const float4*)(arow + (2 * i + 3) * 32);
        }
        // compute the two staged chunks
#pragma unroll
        for (int s = 0; s < 2; ++s) {
            const int c    = 2 * i + s;
            const int slot = c & 3;
            bf16x8 ahf[2], alf[2];
#pragma unroll
            for (int m = 0; m < 2; ++m) {
                const int row = m * 16 + cl;
                ahf[m] = *(const bf16x8*)&Ah[slot][row][p * 8];
                alf[m] = *(const bf16x8*)&Al[slot][row][p * 8];
            }
#pragma unroll
            for (int t = 0; t < 6; ++t) {
                const size_t bb = ((size_t)((w * 6 + t) * KCH + c) * 64 + lane) * 8;
                const bf16x8 bhf = *(const bf16x8*)(bh_g + bb);
                const bf16x8 blf = *(const bf16x8*)(bl_g + bb);
#pragma unroll
                for (int m = 0; m < 2; ++m) {
                    acc[m][t] = __builtin_amdgcn_mfma_f32_16x16x32_bf16(ahf[m], bhf, acc[m][t], 0, 0, 0);
                    acc[m][t] = __builtin_amdgcn_mfma_f32_16x16x32_bf16(ahf[m], blf, acc[m][t], 0, 0, 0);
                    acc[m][t] = __builtin_amdgcn_mfma_f32_16x16x32_bf16(alf[m], bhf, acc[m][t], 0, 0, 0);
                }
            }
        }
        // write next pair into the slots just-freed two iterations ago
        if (i < 11) {
            STAGE(q0, (2 * i + 2) & 3);
            STAGE(q1, (2 * i + 3) & 3);
        }
        __syncthreads();
    }
#undef STAGE

    // ---- epilogue: per-column constants ----
    float b1v[6], gv[6], bev[6], w2v[6];
#pragma unroll
    for (int t = 0; t < 6; ++t) {
        const int n = (w * 6 + t) * 16 + cl;
        b1v[t] = b1[n]; gv[t] = gamma[n]; bev[t] = beta[n]; w2v[t] = W2[n];
    }
    // h = acc + b1
#pragma unroll
    for (int m = 0; m < 2; ++m)
#pragma unroll
        for (int t = 0; t < 6; ++t)
#pragma unroll
            for (int r = 0; r < 4; ++r) acc[m][t][r] += b1v[t];

    // pass 1: row sums -> mean
#pragma unroll
    for (int m = 0; m < 2; ++m) {
        float sm[4] = {0.f, 0.f, 0.f, 0.f};
#pragma unroll
        for (int t = 0; t < 6; ++t)
#pragma unroll
            for (int r = 0; r < 4; ++r) sm[r] += acc[m][t][r];
#pragma unroll
        for (int r = 0; r < 4; ++r) {
#pragma unroll
            for (int off = 1; off <= 8; off <<= 1) sm[r] += __shfl_xor(sm[r], off, 64);
        }
        if (cl == 0) {
#pragma unroll
            for (int r = 0; r < 4; ++r) red[w][m * 16 + p * 4 + r] = sm[r];
        }
    }
    __syncthreads();
    if (tid < 32) mu_s[tid] = (red[0][tid] + red[1][tid] + red[2][tid] + red[3][tid]) * (1.0f / H_);
    __syncthreads();

    // pass 2: variance (two-pass, matches reference)
#pragma unroll
    for (int m = 0; m < 2; ++m) {
        float mur[4];
#pragma unroll
        for (int r = 0; r < 4; ++r) mur[r] = mu_s[m * 16 + p * 4 + r];
        float sm[4] = {0.f, 0.f, 0.f, 0.f};
#pragma unroll
        for (int t = 0; t < 6; ++t)
#pragma unroll
            for (int r = 0; r < 4; ++r) { const float d = acc[m][t][r] - mur[r]; sm[r] += d * d; }
#pragma unroll
        for (int r = 0; r < 4; ++r) {
#pragma unroll
            for (int off = 1; off <= 8; off <<= 1) sm[r] += __shfl_xor(sm[r], off, 64);
        }
        if (cl == 0) {
#pragma unroll
            for (int r = 0; r < 4; ++r) red[w][m * 16 + p * 4 + r] = sm[r];
        }
    }
    __syncthreads();
    if (tid < 32) rs_s[tid] = rsqrtf((red[0][tid] + red[1][tid] + red[2][tid] + red[3][tid]) * (1.0f / H_) + 1e-5f);
    __syncthreads();

    // pass 3: y = LN*gamma+beta, gelu, dot with W2
#pragma unroll
    for (int m = 0; m < 2; ++m) {
        float mur[4], rsr[4];
#pragma unroll
        for (int r = 0; r < 4; ++r) { mur[r] = mu_s[m * 16 + p * 4 + r]; rsr[r] = rs_s[m * 16 + p * 4 + r]; }
        float sm[4] = {0.f, 0.f, 0.f, 0.f};
#pragma unroll
        for (int t = 0; t < 6; ++t)
#pragma unroll
            for (int r = 0; r < 4; ++r) {
                const float y  = (acc[m][t][r] - mur[r]) * rsr[r] * gv[t] + bev[t];
                const float ge = 0.5f * y * (1.0f + erff(y * 0.70710678118654752f));
                sm[r] = fmaf(ge, w2v[t], sm[r]);
            }
#pragma unroll
        for (int r = 0; r < 4; ++r) {
#pragma unroll
            for (int off = 1; off <= 8; off <<= 1) sm[r] += __shfl_xor(sm[r], off, 64);
        }
        if (cl == 0) {
#pragma unroll
            for (int r = 0; r < 4; ++r) red[w][m * 16 + p * 4 + r] = sm[r];
        }
    }
    __syncthreads();
    if (tid < 32) {
        const float s = red[0][tid] + red[1][tid] + red[2][tid] + red[3][tid] + b2[0];
        scores[base + tid] = 1.0f / (1.0f + expf(-s));
    }
}

// ---------------------------------------------------------------------------
// Kernel 2: per-batch exact top-40 via byte-wise radix select on float bits
// (scores > 0 so uint order == float order). Ties -> lower index.
// v4: serial 256-bin threshold scan replaced by wave-parallel suffix sum
// (shfl_down within 64-bin segments + 4-segment combine). Same semantics.
// ---------------------------------------------------------------------------
__global__ __launch_bounds__(256) void select_kernel(const float* __restrict__ scores,
                                                     int* __restrict__ sel)
{
    __shared__ unsigned int bits_s[S_];     // 16 KB
    __shared__ unsigned int hist[256];
    __shared__ unsigned int suf[256];
    __shared__ unsigned int wtot[4];
    __shared__ int s_byte, s_rem;
    __shared__ unsigned int s_ngt, s_neq;
    __shared__ unsigned int candV[64];
    __shared__ int candI[64];
    __shared__ int eqI[256];

    const int b    = blockIdx.x;
    const int tid  = threadIdx.x;
    const int lane = tid & 63;
    const int w4   = tid >> 6;

    for (int i = tid; i < S_; i += 256)
        bits_s[i] = __float_as_uint(scores[b * S_ + i]);
    if (tid == 0) { s_rem = KTOP; s_ngt = 0u; s_neq = 0u; }

    unsigned int prefix = 0u, mask = 0u;
    for (int pb = 3; pb >= 0; --pb) {
        hist[tid] = 0u;
        __syncthreads();
        for (int i = tid; i < S_; i += 256) {
            const unsigned int u = bits_s[i];
            if ((u & mask) == prefix) atomicAdd(&hist[(u >> (8 * pb)) & 255u], 1u);
        }
        __syncthreads();
        // inclusive suffix sum over 256 bins: segment-local via shuffles
        {
            unsigned int v = hist[tid];
#pragma unroll
            for (int off = 1; off < 64; off <<= 1) {
                const unsigned int y = __shfl_down(v, off, 64);
                if (lane + off < 64) v += y;
            }
            if (lane == 0) wtot[w4] = v;   // segment totals
            __syncthreads();
            unsigned int add = 0u;
#pragma unroll
            for (int j = 0; j < 4; ++j) if (j > w4) add += wtot[j];
            v += add;
            suf[tid] = v;                  // suf[t] = #values with byte >= t (given prefix)
            __syncthreads();
            const int rem = s_rem;
            const unsigned int nxt = (tid < 255) ? suf[tid + 1] : 0u;
            if (suf[tid] >= (unsigned)rem && (tid == 255 || nxt < (unsigned)rem)) {
                s_byte = tid;
                s_rem  = rem - (int)nxt;   // subtract count strictly above byte
            }
        }
        __syncthreads();
        prefix |= ((unsigned int)s_byte) << (8 * pb);
        mask   |= 0xFFu << (8 * pb);
        __syncthreads();
    }
    const unsigned int T = prefix;
    const int need = s_rem;                 // 1..: #ties at T to keep

    for (int i = tid; i < S_; i += 256) {
        const unsigned int u = bits_s[i];
        if (u > T) {
            const unsigned int pos = atomicAdd(&s_ngt, 1u);
            candV[pos] = u; candI[pos] = i;          // n_gt <= 39 guaranteed
        } else if (u == T) {
            const unsigned int pos = atomicAdd(&s_neq, 1u);
            if (pos < 256u) eqI[pos] = i;
        }
    }
    __syncthreads();
    const int ngt = (int)s_ngt;
    const int neq = (int)(s_neq < 256u ? s_neq : 256u);
    // keep the `need` smallest indices among ties
    for (int j = tid; j < neq; j += 256) {
        int rank = 0;
        for (int l = 0; l < neq; ++l) rank += (eqI[l] < eqI[j]) ? 1 : 0;
        if (rank < need) { candV[ngt + rank] = T; candI[ngt + rank] = eqI[j]; }
    }
    __syncthreads();
    // final ordering: (score desc, index asc)
    if (tid < KTOP) {
        const unsigned int u = candV[tid];
        const int idx = candI[tid];
        int rank = 0;
        for (int j = 0; j < KTOP; ++j)
            rank += (candV[j] > u || (candV[j] == u && candI[j] < idx)) ? 1 : 0;
        sel[b * KTOP + rank] = idx;
    }
}

// ---------------------------------------------------------------------------
// Kernel 3: gather selected rows + write indices (as float). Grid (40,16).
// ---------------------------------------------------------------------------
__global__ __launch_bounds__(192) void gather_kernel(const float* __restrict__ features,
                                                     const int* __restrict__ sel,
                                                     float* __restrict__ out_tok,
                                                     float* __restrict__ out_idx)
{
    const int i = blockIdx.x;   // 0..39
    const int b = blockIdx.y;   // 0..15
    const int idx = sel[b * KTOP + i];
    const float4* src = (const float4*)(features + ((size_t)b * S_ + idx) * D_);
    float4* dst = (float4*)(out_tok + ((size_t)b * KTOP + i) * D_);
    dst[threadIdx.x] = src[threadIdx.x];
    if (threadIdx.x == 0) out_idx[b * KTOP + i] = (float)idx;
}

// ---------------------------------------------------------------------------
extern "C" void kernel_launch(void* const* d_in, const int* in_sizes, int n_in,
                              void* d_out, int out_size, void* d_ws, size_t ws_size,
                              hipStream_t stream)
{
    const float* features = (const float*)d_in[0];
    const float* W1       = (const float*)d_in[1];
    const float* b1       = (const float*)d_in[2];
    const float* gamma    = (const float*)d_in[3];
    const float* beta     = (const float*)d_in[4];
    const float* W2       = (const float*)d_in[5];
    const float* b2       = (const float*)d_in[6];

    // ws layout
    unsigned short* bh = (unsigned short*)d_ws;            // 294912 elems (576 KB)
    unsigned short* bl = bh + (size_t)D_ * H_;             // 576 KB
    float* scores      = (float*)(bl + (size_t)D_ * H_);   // 256 KB
    int*   sel         = (int*)(scores + NTOK);            // 2.5 KB

    float* out        = (float*)d_out;
    float* out_tokens = out;                               // [16,40,768]
    float* out_idx    = out + (size_t)B_ * KTOP * D_;      // [16,40]

    pack_w1<<<dim3(NTILES, KCH), 64, 0, stream>>>(W1, bh, bl);
    score_kernel<<<NTOK / 32, 256, 0, stream>>>(features, bh, bl, b1, gamma, beta, W2, b2, scores);
    select_kernel<<<B_, 256, 0, stream>>>(scores, sel);
    gather_kernel<<<dim3(KTOP, B_), 192, 0, stream>>>(features, sel, out_tokens, out_idx);
}